// Round 5
// baseline (143.682 us; speedup 1.0000x reference)
//
#include <hip/hip_runtime.h>

#define BB 2
#define NN 512
#define INF 10
#define TI 64
#define TJ 128
#define FC 32    // f-chunk per k_outer block (f-split S = 256/FC = 8)

static __device__ __forceinline__ float dot4(float4 w, float4 v, float acc) {
    acc = fmaf(w.x, v.x, acc);
    acc = fmaf(w.y, v.y, acc);
    acc = fmaf(w.z, v.z, acc);
    acc = fmaf(w.w, v.w, acc);
    return acc;
}

// Kernel 1: per-point MLP chain (10->128->128->64) + projections to ha[256], hb[256]+bp0.
// 256 blocks x 256 threads, 4 points per block. Outputs f-contiguous: haT[point][f].
__global__ __launch_bounds__(256) void k_points(
    const float* __restrict__ x,
    const float* __restrict__ Ws0, const float* __restrict__ bs0,
    const float* __restrict__ Ws1, const float* __restrict__ bs1,
    const float* __restrict__ Ws2, const float* __restrict__ bs2,
    const float* __restrict__ Wp0, const float* __restrict__ bp0,
    float* __restrict__ haT, float* __restrict__ hbT)
{
    __shared__ __align__(16) float xs[4][INF];
    __shared__ __align__(16) float u0s[4][128];
    __shared__ __align__(16) float u1s[4][128];
    __shared__ __align__(16) float u2s[4][64];

    const int t  = threadIdx.x;
    const int p0 = blockIdx.x * 4;

    if (t < 4 * INF) {
        int p = t / INF, c = t % INF;
        xs[p][c] = x[(p0 + p) * INF + c];
    }
    __syncthreads();

    {   // layer 0: 10 -> 128
        const int f = t & 127, ph = t >> 7;
        float a0 = bs0[f], a1 = a0;
        #pragma unroll
        for (int c = 0; c < INF; ++c) {
            float w = Ws0[f * INF + c];
            a0 = fmaf(w, xs[ph * 2 + 0][c], a0);
            a1 = fmaf(w, xs[ph * 2 + 1][c], a1);
        }
        u0s[ph * 2 + 0][f] = fmaxf(a0, 0.f);
        u0s[ph * 2 + 1][f] = fmaxf(a1, 0.f);
    }
    __syncthreads();

    {   // layer 1: 128 -> 128
        const int f = t & 127, ph = t >> 7;
        float a0 = bs1[f], a1 = a0;
        const float4* wv = (const float4*)(Ws1 + f * 128);
        #pragma unroll 8
        for (int c4 = 0; c4 < 32; ++c4) {
            float4 w  = wv[c4];
            float4 x0 = *(const float4*)&u0s[ph * 2 + 0][c4 * 4];
            float4 x1 = *(const float4*)&u0s[ph * 2 + 1][c4 * 4];
            a0 = dot4(w, x0, a0);
            a1 = dot4(w, x1, a1);
        }
        u1s[ph * 2 + 0][f] = fmaxf(a0, 0.f);
        u1s[ph * 2 + 1][f] = fmaxf(a1, 0.f);
    }
    __syncthreads();

    {   // layer 2: 128 -> 64
        const int f = t & 63, p = t >> 6;
        float a = bs2[f];
        const float4* wv = (const float4*)(Ws2 + f * 128);
        #pragma unroll 8
        for (int c4 = 0; c4 < 32; ++c4) {
            float4 w  = wv[c4];
            float4 xv = *(const float4*)&u1s[p][c4 * 4];
            a = dot4(w, xv, a);
        }
        u2s[p][f] = fmaxf(a, 0.f);
    }
    __syncthreads();

    {   // projection to ha / hb(+bp0)
        const int f = t;
        float ah[4], bh[4];
        const float bb = bp0[f];
        #pragma unroll
        for (int p = 0; p < 4; ++p) { ah[p] = 0.f; bh[p] = bb; }
        const float4* wv = (const float4*)(Wp0 + f * 128);
        #pragma unroll 4
        for (int c4 = 0; c4 < 16; ++c4) {
            float4 wa = wv[c4];
            float4 wb = wv[16 + c4];
            #pragma unroll
            for (int p = 0; p < 4; ++p) {
                float4 u = *(const float4*)&u2s[p][c4 * 4];
                ah[p] = dot4(wa, u, ah[p]);
                bh[p] = dot4(wb, u, bh[p]);
            }
        }
        #pragma unroll
        for (int p = 0; p < 4; ++p) {
            haT[(size_t)(p0 + p) * 256 + f] = ah[p];
            hbT[(size_t)(p0 + p) * 256 + f] = bh[p];
        }
    }
}

// Kernel 2: partial[z][i][j] = sum_{f in chunk z&7} w[f]*relu(ha[b,f,j] + hb'(b,f,i)),  z = b*8+s
// grid (4,8,16): 64(i) x 128(j) tile, FC=32 f per block. 256 threads, 4 waves as 2x2,
// lane = 8(li) x 8(lj), register tile 4(i) x 8(j). No atomics: plain stores to partials.
// LDS rows are 128 B (32 f); 16B-granule XOR swizzle c^((row>>3)&7):
//   sA reads -> 8 distinct granule columns (conflict-free); sB reads -> 2-way (free).
__global__ __launch_bounds__(256, 2) void k_outer(
    const float* __restrict__ haT, const float* __restrict__ hbT,
    const float* __restrict__ Wp1, float* __restrict__ partials)
{
    __shared__ __align__(16) float sA[TJ * FC];  // ha, local j rows
    __shared__ __align__(16) float sB[TI * FC];  // hb(+bp0), local i rows

    const int t  = threadIdx.x;
    const int jb = blockIdx.x * TJ;
    const int ib = blockIdx.y * TI;
    const int z  = blockIdx.z;        // b*8 + s
    const int b  = z >> 3;
    const int f0 = (z & 7) * FC;

    // stage sA: 128 rows x 8 granules
    #pragma unroll
    for (int k = 0; k < 4; ++k) {
        const int u = t + 256 * k;
        const int r = u >> 3, c = u & 7;
        const int cs = c ^ ((r >> 3) & 7);
        float4 v = *(const float4*)(haT + ((size_t)(b * NN + jb + r)) * 256 + f0 + c * 4);
        *(float4*)&sA[r * FC + cs * 4] = v;
    }
    // stage sB: 64 rows x 8 granules
    #pragma unroll
    for (int k = 0; k < 2; ++k) {
        const int u = t + 256 * k;
        const int r = u >> 3, c = u & 7;
        const int cs = c ^ ((r >> 3) & 7);
        float4 v = *(const float4*)(hbT + ((size_t)(b * NN + ib + r)) * 256 + f0 + c * 4);
        *(float4*)&sB[r * FC + cs * 4] = v;
    }
    __syncthreads();

    const int lane = t & 63, wid = t >> 6;
    const int li = lane >> 3, lj = lane & 7;
    const int wr = wid >> 1, wc = wid & 1;
    const int i0 = wr * 32 + li * 4;     // 4 consecutive i rows
    const int j0 = wc * 64 + lj * 8;     // 8 consecutive j rows

    const char* baseA = (const char*)sA + j0 * (FC * 4);
    const char* baseB = (const char*)sB + i0 * (FC * 4);
    const int xa = lj;                    // (row>>3)&7 for rows j0..j0+7 (uniform per thread)
    const int xb = wr * 4 + (li >> 1);    // (row>>3)&7 for rows i0..i0+3 (uniform per thread)

    const float4* wg = (const float4*)(Wp1 + f0);   // uniform -> scalar loads

    float acc[4][8];
    #pragma unroll
    for (int di = 0; di < 4; ++di)
        #pragma unroll
        for (int dj = 0; dj < 8; ++dj) acc[di][dj] = 0.f;

    #pragma unroll
    for (int g = 0; g < 8; ++g) {
        const float4 w = wg[g];
        const int offA = (g ^ xa) << 4;
        const int offB = (g ^ xb) << 4;
        float4 av[8], bv[4];
        #pragma unroll
        for (int dj = 0; dj < 8; ++dj) av[dj] = *(const float4*)(baseA + dj * 128 + offA);
        #pragma unroll
        for (int di = 0; di < 4; ++di) bv[di] = *(const float4*)(baseB + di * 128 + offB);
        #pragma unroll
        for (int di = 0; di < 4; ++di) {
            #pragma unroll
            for (int dj = 0; dj < 8; ++dj) {
                acc[di][dj] = fmaf(w.x, fmaxf(av[dj].x + bv[di].x, 0.f), acc[di][dj]);
                acc[di][dj] = fmaf(w.y, fmaxf(av[dj].y + bv[di].y, 0.f), acc[di][dj]);
                acc[di][dj] = fmaf(w.z, fmaxf(av[dj].z + bv[di].z, 0.f), acc[di][dj]);
                acc[di][dj] = fmaf(w.w, fmaxf(av[dj].w + bv[di].w, 0.f), acc[di][dj]);
            }
        }
    }

    // store partial tile: 4 rows x 2 float4, coalesced along j
    float* pz = partials + (size_t)z * NN * NN;
    #pragma unroll
    for (int di = 0; di < 4; ++di) {
        float* row = pz + (size_t)(ib + i0 + di) * NN + (jb + j0);
        float4 r0 = { acc[di][0], acc[di][1], acc[di][2], acc[di][3] };
        float4 r1 = { acc[di][4], acc[di][5], acc[di][6], acc[di][7] };
        *(float4*)(row + 0) = r0;
        *(float4*)(row + 4) = r1;
    }
}

// Kernel 3: out = bp1 + sum_{s=0..7} partial[b*8+s]
__global__ __launch_bounds__(256) void k_reduce(
    const float* __restrict__ partials, const float* __restrict__ bp1,
    float* __restrict__ out)
{
    const int q   = blockIdx.x * 256 + threadIdx.x;  // float4 index, 0..131071
    const int b   = q >> 16;                          // 65536 float4 per batch
    const int rem = q & 65535;
    const float4* p = (const float4*)partials + ((size_t)b * 8) * 65536 + rem;
    const float bv = bp1[0];
    float4 acc = { bv, bv, bv, bv };
    #pragma unroll
    for (int s = 0; s < 8; ++s) {
        float4 v = p[(size_t)s * 65536];
        acc.x += v.x; acc.y += v.y; acc.z += v.z; acc.w += v.w;
    }
    ((float4*)out)[q] = acc;
}

extern "C" void kernel_launch(void* const* d_in, const int* in_sizes, int n_in,
                              void* d_out, int out_size, void* d_ws, size_t ws_size,
                              hipStream_t stream) {
    const float* x   = (const float*)d_in[0];
    const float* Ws0 = (const float*)d_in[1];
    const float* bs0 = (const float*)d_in[2];
    const float* Ws1 = (const float*)d_in[3];
    const float* bs1 = (const float*)d_in[4];
    const float* Ws2 = (const float*)d_in[5];
    const float* bs2 = (const float*)d_in[6];
    const float* Wp0 = (const float*)d_in[7];
    const float* bp0 = (const float*)d_in[8];
    const float* Wp1 = (const float*)d_in[9];
    const float* bp1 = (const float*)d_in[10];

    float* haT      = (float*)d_ws;                      // [1024][256] = 1 MB
    float* hbT      = haT + (size_t)BB * NN * 256;       // [1024][256] = 1 MB
    float* partials = hbT + (size_t)BB * NN * 256;       // [16][512][512] = 16 MB

    k_points<<<dim3(BB * NN / 4), dim3(256), 0, stream>>>(
        x, Ws0, bs0, Ws1, bs1, Ws2, bs2, Wp0, bp0, haT, hbT);

    k_outer<<<dim3(NN / TJ, NN / TI, BB * (256 / FC)), dim3(256), 0, stream>>>(
        haT, hbT, Wp1, partials);

    k_reduce<<<dim3(BB * NN * NN / 4 / 256), dim3(256), 0, stream>>>(
        partials, bp1, (float*)d_out);
}

// Round 6
// 108.676 us; speedup vs baseline: 1.3221x; 1.3221x over previous
//
#include <hip/hip_runtime.h>

#define BB 2
#define NN 512
#define INF 10
#define TI 64    // i-extent of output tile
#define TJ 32    // j-extent of output tile
#define FCH 128  // f per staging phase (2 phases, full f=256 accumulated in-block)

static __device__ __forceinline__ float dot4(float4 w, float4 v, float acc) {
    acc = fmaf(w.x, v.x, acc);
    acc = fmaf(w.y, v.y, acc);
    acc = fmaf(w.z, v.z, acc);
    acc = fmaf(w.w, v.w, acc);
    return acc;
}

// Kernel 1: per-point MLP chain (10->128->128->64) + projections to ha[256], hb[256]+bp0.
// 256 blocks x 256 threads, 4 points per block. Outputs f-contiguous: haT[point][f].
__global__ __launch_bounds__(256) void k_points(
    const float* __restrict__ x,
    const float* __restrict__ Ws0, const float* __restrict__ bs0,
    const float* __restrict__ Ws1, const float* __restrict__ bs1,
    const float* __restrict__ Ws2, const float* __restrict__ bs2,
    const float* __restrict__ Wp0, const float* __restrict__ bp0,
    float* __restrict__ haT, float* __restrict__ hbT)
{
    __shared__ __align__(16) float xs[4][INF];
    __shared__ __align__(16) float u0s[4][128];
    __shared__ __align__(16) float u1s[4][128];
    __shared__ __align__(16) float u2s[4][64];

    const int t  = threadIdx.x;
    const int p0 = blockIdx.x * 4;

    if (t < 4 * INF) {
        int p = t / INF, c = t % INF;
        xs[p][c] = x[(p0 + p) * INF + c];
    }
    __syncthreads();

    {   // layer 0: 10 -> 128
        const int f = t & 127, ph = t >> 7;
        float a0 = bs0[f], a1 = a0;
        #pragma unroll
        for (int c = 0; c < INF; ++c) {
            float w = Ws0[f * INF + c];
            a0 = fmaf(w, xs[ph * 2 + 0][c], a0);
            a1 = fmaf(w, xs[ph * 2 + 1][c], a1);
        }
        u0s[ph * 2 + 0][f] = fmaxf(a0, 0.f);
        u0s[ph * 2 + 1][f] = fmaxf(a1, 0.f);
    }
    __syncthreads();

    {   // layer 1: 128 -> 128
        const int f = t & 127, ph = t >> 7;
        float a0 = bs1[f], a1 = a0;
        const float4* wv = (const float4*)(Ws1 + f * 128);
        #pragma unroll 8
        for (int c4 = 0; c4 < 32; ++c4) {
            float4 w  = wv[c4];
            float4 x0 = *(const float4*)&u0s[ph * 2 + 0][c4 * 4];
            float4 x1 = *(const float4*)&u0s[ph * 2 + 1][c4 * 4];
            a0 = dot4(w, x0, a0);
            a1 = dot4(w, x1, a1);
        }
        u1s[ph * 2 + 0][f] = fmaxf(a0, 0.f);
        u1s[ph * 2 + 1][f] = fmaxf(a1, 0.f);
    }
    __syncthreads();

    {   // layer 2: 128 -> 64
        const int f = t & 63, p = t >> 6;
        float a = bs2[f];
        const float4* wv = (const float4*)(Ws2 + f * 128);
        #pragma unroll 8
        for (int c4 = 0; c4 < 32; ++c4) {
            float4 w  = wv[c4];
            float4 xv = *(const float4*)&u1s[p][c4 * 4];
            a = dot4(w, xv, a);
        }
        u2s[p][f] = fmaxf(a, 0.f);
    }
    __syncthreads();

    {   // projection to ha / hb(+bp0)
        const int f = t;
        float ah[4], bh[4];
        const float bb = bp0[f];
        #pragma unroll
        for (int p = 0; p < 4; ++p) { ah[p] = 0.f; bh[p] = bb; }
        const float4* wv = (const float4*)(Wp0 + f * 128);
        #pragma unroll 4
        for (int c4 = 0; c4 < 16; ++c4) {
            float4 wa = wv[c4];
            float4 wb = wv[16 + c4];
            #pragma unroll
            for (int p = 0; p < 4; ++p) {
                float4 u = *(const float4*)&u2s[p][c4 * 4];
                ah[p] = dot4(wa, u, ah[p]);
                bh[p] = dot4(wb, u, bh[p]);
            }
        }
        #pragma unroll
        for (int p = 0; p < 4; ++p) {
            haT[(size_t)(p0 + p) * 256 + f] = ah[p];
            hbT[(size_t)(p0 + p) * 256 + f] = bh[p];
        }
    }
}

// Kernel 2: out[b,i,j] = bp1 + sum_{f=0..255} w[f]*relu(ha[b,f,j] + hb'(b,f,i)).
// Full f per block (2 staged phases of 128 f) -> d_out written once, densely. No ws traffic
// beyond reading haT/hbT (2 MB, LLC-resident). Grid (16,8,2) = 256 blocks = 1/CU.
// 256 threads = 4 waves; wave w owns i-range [w*16, w*16+16); lane: li=lane>>4 (i), lj=lane&15 (j).
// Register tile 4(i) x 2(j): per 4-f group 6 ds_read_b128 vs 96 VALU ops -> near-balanced.
// LDS granule swizzle (16B units): sA col = g ^ ((row>>1)&15), sB col = g ^ ((row>>2)&15).
// Applied by pre-swizzling the GLOBAL source granule and writing LDS dense (coalescing is
// preserved: permutation stays within each 512B row). Reads XOR g<<4 into base bits [4:8]:
// sA reads 2-way conflicts (free), sB reads conflict-free.
__global__ __launch_bounds__(256) void k_outer(
    const float* __restrict__ haT, const float* __restrict__ hbT,
    const float* __restrict__ Wp1, const float* __restrict__ bp1,
    float* __restrict__ out)
{
    __shared__ __align__(512) float sA[TJ * FCH];   // 32 j-rows x 128 f = 16 KB
    __shared__ __align__(512) float sB[TI * FCH];   // 64 i-rows x 128 f = 32 KB

    const int t  = threadIdx.x;
    const int jb = blockIdx.x * TJ;
    const int ib = blockIdx.y * TI;
    const int b  = blockIdx.z;

    const int lane = t & 63, w = t >> 6;
    const int lj = lane & 15;           // j-group 0..15
    const int li = lane >> 4;           // i-group 0..3
    const int j0 = lj * 2;              // 2 consecutive j rows
    const int i0 = w * 16 + li * 4;     // 4 consecutive i rows
    const int xa = lj;                  // (row>>1)&15 for rows j0, j0+1
    const int xb = w * 4 + li;          // (row>>2)&15 for rows i0..i0+3

    // read bases with swizzle key folded into bits [4:7] (row base is 512B-aligned)
    const uintptr_t aB0 = (uintptr_t)sA + (size_t)j0 * (FCH * 4) + (xa << 4);
    const uintptr_t aB1 = aB0 + FCH * 4;
    uintptr_t bBs[4];
    #pragma unroll
    for (int di = 0; di < 4; ++di)
        bBs[di] = (uintptr_t)sB + (size_t)(i0 + di) * (FCH * 4) + (xb << 4);

    float acc[4][2];
    #pragma unroll
    for (int di = 0; di < 4; ++di) { acc[di][0] = 0.f; acc[di][1] = 0.f; }

    const int sp = t & 31;              // staging granule slot (constant per thread)

    for (int ph = 0; ph < 2; ++ph) {
        const int f0 = ph * FCH;
        if (ph) __syncthreads();        // protect LDS reuse across phases

        // stage sA: 32 rows x 32 granules; dense LDS write, pre-swizzled global source
        #pragma unroll
        for (int k = 0; k < 4; ++k) {
            const int r  = (t >> 5) + 8 * k;                 // row 0..31
            const int sg = sp ^ ((r >> 1) & 15);             // source granule
            float4 v = *(const float4*)(haT + ((size_t)(b * NN + jb + r)) * 256 + f0 + sg * 4);
            *(float4*)&sA[r * FCH + sp * 4] = v;
        }
        // stage sB: 64 rows x 32 granules
        #pragma unroll
        for (int k = 0; k < 8; ++k) {
            const int r  = (t >> 5) + 8 * k;                 // row 0..63
            const int sg = sp ^ ((r >> 2) & 15);
            float4 v = *(const float4*)(hbT + ((size_t)(b * NN + ib + r)) * 256 + f0 + sg * 4);
            *(float4*)&sB[r * FCH + sp * 4] = v;
        }
        __syncthreads();

        const float4* wg = (const float4*)(Wp1 + f0);        // uniform -> scalar loads

        #pragma unroll 8
        for (int g = 0; g < 32; ++g) {
            const float4 w4 = wg[g];
            const uintptr_t gx = (uintptr_t)(g << 4);
            const float4 a0 = *(const float4*)(aB0 ^ gx);
            const float4 a1 = *(const float4*)(aB1 ^ gx);
            float4 bv[4];
            #pragma unroll
            for (int di = 0; di < 4; ++di) bv[di] = *(const float4*)(bBs[di] ^ gx);

            #pragma unroll
            for (int di = 0; di < 4; ++di) {
                acc[di][0] = fmaf(w4.x, fmaxf(a0.x + bv[di].x, 0.f), acc[di][0]);
                acc[di][1] = fmaf(w4.x, fmaxf(a1.x + bv[di].x, 0.f), acc[di][1]);
                acc[di][0] = fmaf(w4.y, fmaxf(a0.y + bv[di].y, 0.f), acc[di][0]);
                acc[di][1] = fmaf(w4.y, fmaxf(a1.y + bv[di].y, 0.f), acc[di][1]);
                acc[di][0] = fmaf(w4.z, fmaxf(a0.z + bv[di].z, 0.f), acc[di][0]);
                acc[di][1] = fmaf(w4.z, fmaxf(a1.z + bv[di].z, 0.f), acc[di][1]);
                acc[di][0] = fmaf(w4.w, fmaxf(a0.w + bv[di].w, 0.f), acc[di][0]);
                acc[di][1] = fmaf(w4.w, fmaxf(a1.w + bv[di].w, 0.f), acc[di][1]);
            }
        }
    }

    // store: per thread 4 rows x float2; wave covers 128B dense per i-row
    const float bias = bp1[0];
    float* o = out + (size_t)b * NN * NN;
    #pragma unroll
    for (int di = 0; di < 4; ++di) {
        float2 v = { acc[di][0] + bias, acc[di][1] + bias };
        *(float2*)&o[(size_t)(ib + i0 + di) * NN + (jb + j0)] = v;
    }
}

extern "C" void kernel_launch(void* const* d_in, const int* in_sizes, int n_in,
                              void* d_out, int out_size, void* d_ws, size_t ws_size,
                              hipStream_t stream) {
    const float* x   = (const float*)d_in[0];
    const float* Ws0 = (const float*)d_in[1];
    const float* bs0 = (const float*)d_in[2];
    const float* Ws1 = (const float*)d_in[3];
    const float* bs1 = (const float*)d_in[4];
    const float* Ws2 = (const float*)d_in[5];
    const float* bs2 = (const float*)d_in[6];
    const float* Wp0 = (const float*)d_in[7];
    const float* bp0 = (const float*)d_in[8];
    const float* Wp1 = (const float*)d_in[9];
    const float* bp1 = (const float*)d_in[10];

    float* haT = (float*)d_ws;                      // [1024][256] = 1 MB
    float* hbT = haT + (size_t)BB * NN * 256;       // [1024][256] = 1 MB

    k_points<<<dim3(BB * NN / 4), dim3(256), 0, stream>>>(
        x, Ws0, bs0, Ws1, bs1, Ws2, bs2, Wp0, bp0, haT, hbT);

    k_outer<<<dim3(NN / TJ, NN / TI, BB), dim3(256), 0, stream>>>(
        haT, hbT, Wp1, bp1, (float*)d_out);
}